// Round 19
// baseline (200.722 us; speedup 1.0000x reference)
//
#include <hip/hip_runtime.h>

// MHA forward: x[4,2048,1024] f32, W_QKV[3072,1024] f32, W_O[1024,1024] f32,
// pos[2048] i32 -> out[4,2048,1024] f32.
// R13: attn KVBLK 64->128 via two R11-shaped 64x64 sub-tiles per iteration
//      (identical layout/swizzle/math; one barrier per 128 keys). Iterations
//      per block halve (max 32->16). 4 waves, QBLK=128, 1024 blocks.
//      GEMMs (dbuf+T2), rope, casts unchanged from R11.

typedef __attribute__((ext_vector_type(4)))  float          f32x4;
typedef __attribute__((ext_vector_type(16))) float          f32x16;
typedef __attribute__((ext_vector_type(8)))  __bf16         bf16x8;
typedef __attribute__((ext_vector_type(8)))  unsigned short u16x8;
typedef __attribute__((ext_vector_type(4)))  unsigned short u16x4;

__device__ __forceinline__ unsigned short f2bf(float f) {
  unsigned int u = __builtin_bit_cast(unsigned int, f);
  u = (u + 0x7fffu + ((u >> 16) & 1u)) >> 16;
  return (unsigned short)u;
}
__device__ __forceinline__ float bf2f(unsigned short b) {
  return __builtin_bit_cast(float, ((unsigned int)b) << 16);
}
__device__ __forceinline__ unsigned int cvtpk_bf16(float lo, float hi) {
  unsigned int r;
  asm("v_cvt_pk_bf16_f32 %0, %1, %2" : "=v"(r) : "v"(lo), "v"(hi));
  return r;
}
__device__ __forceinline__ void gload_lds16(const void* g, void* l) {
  __builtin_amdgcn_global_load_lds((const __attribute__((address_space(1))) void*)g,
                                   (__attribute__((address_space(3))) void*)l, 16, 0, 0);
}

// ---------------- cast f32 -> bf16 ----------------
__global__ void cast_f32_bf16_k(const float* __restrict__ in, unsigned short* __restrict__ out, int n) {
  int i = (blockIdx.x * blockDim.x + threadIdx.x) * 4;
  const int stride = gridDim.x * blockDim.x * 4;
  for (; i < n; i += stride) {
    float4 v = *(const float4*)(in + i);
    u16x4 o = { f2bf(v.x), f2bf(v.y), f2bf(v.z), f2bf(v.w) };
    *(u16x4*)(out + i) = o;
  }
}

// ---------------- NT GEMM (dbuf + T2 swizzle): C = A * B^T ----------------
template <typename OutT>
__global__ __launch_bounds__(256) void gemm_dbuf(
    const unsigned short* __restrict__ A,
    const unsigned short* __restrict__ B,
    OutT* __restrict__ C,
    int M, int N, int K) {
  __shared__ unsigned short As[2][128 * 64];
  __shared__ unsigned short Bs[2][128 * 64];
  const int tid  = threadIdx.x;
  const int wid  = tid >> 6;
  const int lane = tid & 63;
  const int l15  = lane & 15, l4 = lane >> 4;
  const int wr   = wid >> 1, wc = wid & 1;
  const int flat = blockIdx.y * gridDim.x + blockIdx.x;
  const int cpx  = (gridDim.x * gridDim.y) >> 3;
  const int swz  = (flat & 7) * cpx + (flat >> 3);
  const int bx   = swz % gridDim.x, by = swz / gridDim.x;
  const int row0 = by * 128, col0 = bx * 128;
  const int wrb  = wr * 64, wcb = wc * 64;

  f32x4 acc[4][4];
  const f32x4 z = {0.f, 0.f, 0.f, 0.f};
#pragma unroll
  for (int m = 0; m < 4; ++m)
#pragma unroll
    for (int n = 0; n < 4; ++n) acc[m][n] = z;

#define STAGE_G(t_, buf_)                                                               \
  {                                                                                     \
    const int k0g = (t_) * 64;                                                          \
    _Pragma("unroll")                                                                   \
    for (int ig = 0; ig < 4; ++ig) {                                                    \
      const int flg = ig * 256 + tid;                                                   \
      const int rg  = flg >> 3;                                                         \
      const int cbg = (flg & 7) * 16;                                                   \
      const int scg = (cbg ^ ((rg & 7) << 4)) >> 1;                                     \
      gload_lds16(&A[(size_t)(row0 + rg) * K + k0g + scg],                              \
                  &As[buf_][rg * 64 + (cbg >> 1)]);                                     \
      gload_lds16(&B[(size_t)(col0 + rg) * K + k0g + scg],                              \
                  &Bs[buf_][rg * 64 + (cbg >> 1)]);                                     \
    }                                                                                   \
  }

  const int NT = K >> 6;
  STAGE_G(0, 0);
  __syncthreads();

  for (int t = 0; t < NT; ++t) {
    const int cbuf = t & 1;
    if (t + 1 < NT) STAGE_G(t + 1, cbuf ^ 1);
#pragma unroll
    for (int ks = 0; ks < 2; ++ks) {
      bf16x8 af[4], bfr[4];
#pragma unroll
      for (int m = 0; m < 4; ++m) {
        const int row = wrb + m * 16 + l15;
        const int off = (row << 7) + ((ks * 64 + l4 * 16) ^ ((row & 7) << 4));
        af[m] = *(const bf16x8*)((const char*)&As[cbuf][0] + off);
      }
#pragma unroll
      for (int n = 0; n < 4; ++n) {
        const int row = wcb + n * 16 + l15;
        const int off = (row << 7) + ((ks * 64 + l4 * 16) ^ ((row & 7) << 4));
        bfr[n] = *(const bf16x8*)((const char*)&Bs[cbuf][0] + off);
      }
      __builtin_amdgcn_s_setprio(1);
#pragma unroll
      for (int m = 0; m < 4; ++m)
#pragma unroll
        for (int n = 0; n < 4; ++n)
          acc[m][n] = __builtin_amdgcn_mfma_f32_16x16x32_bf16(af[m], bfr[n], acc[m][n], 0, 0, 0);
      __builtin_amdgcn_s_setprio(0);
    }
    __syncthreads();
  }
#undef STAGE_G

#pragma unroll
  for (int m = 0; m < 4; ++m) {
    const int row = row0 + wrb + m * 16 + l4 * 4;
#pragma unroll
    for (int n = 0; n < 4; ++n) {
      const int col = col0 + wcb + n * 16 + l15;
#pragma unroll
      for (int r = 0; r < 4; ++r) {
        float v = acc[m][n][r];
        if constexpr (sizeof(OutT) == 2)
          C[(size_t)(row + r) * N + col] = f2bf(v);
        else
          C[(size_t)(row + r) * N + col] = v;
      }
    }
  }
}

// ---------------- RoPE + repack qkv[B*S][3072] -> Q/K [B*H][S][64] ----------------
#define ATTN_SCL 0.18033688011112042f
#define NEG_L2_10K_32 (-0.41524101186092029f)  // -log2(10000)/32
__global__ __launch_bounds__(512) void rope_repack(
    const unsigned short* __restrict__ qkv,
    const int* __restrict__ pos,
    unsigned short* __restrict__ Qr,
    unsigned short* __restrict__ Kr) {
  const int bs = blockIdx.x;
  const int b  = bs >> 11, s = bs & 2047;
  const int t  = threadIdx.x;
  const int h  = t >> 5, kk = t & 31;
  const float p    = (float)pos[s];
  const float freq = exp2f((float)kk * NEG_L2_10K_32);
  float sn, c;
  __sincosf(p * freq, &sn, &c);
  const unsigned short* base = qkv + (size_t)bs * 3072;
  const size_t oidx = ((size_t)(b * 16 + h) * 2048 + s) * 64 + 2 * kk;
  float e = bf2f(base[h * 64 + 2 * kk]);
  float o = bf2f(base[h * 64 + 2 * kk + 1]);
  Qr[oidx]     = f2bf((c * e - sn * o) * ATTN_SCL);
  Qr[oidx + 1] = f2bf((sn * e + c * o) * ATTN_SCL);
  e = bf2f(base[1024 + h * 64 + 2 * kk]);
  o = bf2f(base[1024 + h * 64 + 2 * kk + 1]);
  Kr[oidx]     = f2bf(c * e - sn * o);
  Kr[oidx + 1] = f2bf(sn * e + c * o);
}

// ---------------- causal flash attention (R13: KVBLK=128 as 2x64 sub-tiles) --------
// grid 1024 blocks x 256 thr (4 waves x 32 q-rows); one barrier per 128 keys.
#define DEFER_THR 12.0f  // exp2-domain (~8.3 nats)

__global__ __launch_bounds__(256) void attn_fwd(
    const unsigned short* __restrict__ Qr,
    const unsigned short* __restrict__ Kr,
    const unsigned short* __restrict__ qkv,   // V source: [B*S][3072], col 2048+h*64
    unsigned short* __restrict__ Out) {       // [B*S][1024]
  __shared__ unsigned short Ks[2][2][64 * 64];  // [dbuf][sub 64-key tile], swizzled
  __shared__ unsigned short Vt[2][2][64 * 64];  // [dbuf][sub][d][key], swizzled
  const int flat = blockIdx.x;
  const int bh   = (flat & 7) * 8 + ((flat >> 3) & 7);
  const int qt   = 15 - (flat >> 6);          // longest-first, qt 0..15
  const int tid  = threadIdx.x, w = tid >> 6, lane = tid & 63;
  const int l31  = lane & 31, hi = lane >> 5;
  const size_t hbase = (size_t)bh * 2048 * 64;
  const int b = bh >> 4, h = bh & 15;
  const int b2048 = b * 2048;
  const unsigned short* Vg = qkv + 2048 + h * 64;  // + row*3072 + d

  const int q_g = qt * 128 + w * 32 + l31;    // this lane's query row
  const int q_l = w * 32 + l31;               // local within the 128-q block

  // Q fragments (pre-scaled): qf[ks] = Q[q_g][ks*16 + hi*8 .. +7]
  bf16x8 qf[4];
#pragma unroll
  for (int ks = 0; ks < 4; ++ks)
    qf[ks] = *(const bf16x8*)&Qr[hbase + (size_t)q_g * 64 + ks * 16 + hi * 8];

  f32x16 accO[2];
#pragma unroll
  for (int blk = 0; blk < 2; ++blk)
#pragma unroll
    for (int r = 0; r < 16; ++r) accO[blk][r] = 0.f;
  float m_run = -__builtin_inff(), l_run = 0.f;

  f32x16 zero16;
#pragma unroll
  for (int r = 0; r < 16; ++r) zero16[r] = 0.f;

  // --- staging assignments ---
  // K: wave w stages rows w*32..w*32+31 of the 128-row K tile -> sub (w>>1),
  //    local rows (w&1)*32 .. +31, as 4 gload_lds of 8 rows each.
  const int ksub    = w >> 1;
  const int krow_in = (w & 1) * 32 + (lane >> 3);   // + p*8
  const int kcb0    = (lane & 7) * 16;
  // V: thread owns key-pair {2kp,2kp+1} x 8 d-rows in EACH sub-tile.
  const int kp  = tid & 31;
  const int vd0 = (tid >> 5) * 8;
  const int vk0 = kp * 2;

#define STAGE_K(kt_, buf_)                                                              \
  {                                                                                     \
    _Pragma("unroll")                                                                   \
    for (int pg = 0; pg < 4; ++pg) {                                                    \
      const int rowg = krow_in + pg * 8;                                                \
      const int scbg = kcb0 ^ ((rowg & 7) << 4);                                        \
      gload_lds16(Kr + hbase + (size_t)((kt_) * 128 + ksub * 64 + rowg) * 64            \
                      + (scbg >> 1),                                                    \
                  &Ks[buf_][ksub][((w & 1) * 32 + pg * 8) * 64]);                       \
    }                                                                                   \
  }

#define LOAD_V(kt_, s_, r0_, r1_)                                                       \
  {                                                                                     \
    const unsigned short* gvg =                                                         \
        Vg + (size_t)(b2048 + (kt_) * 128 + (s_) * 64 + vk0) * 3072 + vd0;              \
    r0_ = *(const u16x8*)gvg;                                                           \
    r1_ = *(const u16x8*)(gvg + 3072);                                                  \
  }

#define WRITE_V(buf_, s_, r0_, r1_)                                                     \
  {                                                                                     \
    _Pragma("unroll")                                                                   \
    for (int ig = 0; ig < 8; ++ig) {                                                    \
      const int bag = ((vd0 + ig) << 7) + ((vk0 * 2) ^ ((ig & 7) << 4));                \
      const unsigned int wvg =                                                          \
          (unsigned int)(r0_)[ig] | ((unsigned int)(r1_)[ig] << 16);                    \
      *(unsigned int*)((char*)&Vt[buf_][s_][0] + bag) = wvg;                            \
    }                                                                                   \
  }

  // ---- one 64-key compute substep (R11 body, parameterized by sub-tile) ----
#define SUBSTEP(cbuf_, s_, MASKED_)                                                     \
  {                                                                                     \
    f32x16 sc[2];                                                                       \
    __builtin_amdgcn_s_setprio(1);                                                      \
    _Pragma("unroll")                                                                   \
    for (int kb = 0; kb < 2; ++kb) {                                                    \
      {                                                                                 \
        const int row = kb * 32 + l31;                                                  \
        const int off = (row << 7) + ((16 * hi) ^ ((row & 7) << 4));                    \
        bf16x8 kbf = *(const bf16x8*)((const char*)&Ks[cbuf_][s_][0] + off);            \
        sc[kb] = __builtin_amdgcn_mfma_f32_32x32x16_bf16(kbf, qf[0], zero16, 0, 0, 0);  \
      }                                                                                 \
      _Pragma("unroll")                                                                 \
      for (int ks = 1; ks < 4; ++ks) {                                                  \
        const int row = kb * 32 + l31;                                                  \
        const int off = (row << 7) + ((32 * ks + 16 * hi) ^ ((row & 7) << 4));          \
        bf16x8 kbf = *(const bf16x8*)((const char*)&Ks[cbuf_][s_][0] + off);            \
        sc[kb] = __builtin_amdgcn_mfma_f32_32x32x16_bf16(kbf, qf[ks], sc[kb], 0, 0, 0); \
      }                                                                                 \
    }                                                                                   \
    __builtin_amdgcn_s_setprio(0);                                                      \
    if (MASKED_) {                                                                      \
      _Pragma("unroll")                                                                 \
      for (int kb = 0; kb < 2; ++kb)                                                    \
        _Pragma("unroll")                                                               \
        for (int r = 0; r < 16; ++r) {                                                  \
          const int keyl = (s_) * 64 + kb * 32 + (r & 3) + 8 * ((r >> 2) & 3) + 4 * hi; \
          if (keyl > q_l) sc[kb][r] = -__builtin_inff();                                \
        }                                                                               \
    }                                                                                   \
    float pm[8];                                                                        \
    _Pragma("unroll")                                                                   \
    for (int i = 0; i < 8; ++i)                                                         \
      pm[i] = fmaxf(fmaxf(sc[0][2 * i], sc[0][2 * i + 1]),                              \
                    fmaxf(sc[1][2 * i], sc[1][2 * i + 1]));                             \
    float rmax = fmaxf(fmaxf(fmaxf(pm[0], pm[1]), fmaxf(pm[2], pm[3])),                 \
                       fmaxf(fmaxf(pm[4], pm[5]), fmaxf(pm[6], pm[7])));                \
    rmax = fmaxf(rmax, __shfl_xor(rmax, 32, 64));                                       \
    if (!__all(rmax <= m_run + DEFER_THR)) {                                            \
      const float mnew = fmaxf(m_run, rmax);                                            \
      const float alpha = exp2f(m_run - mnew);                                          \
      m_run = mnew;                                                                     \
      l_run *= alpha;                                                                   \
      _Pragma("unroll")                                                                 \
      for (int blk = 0; blk < 2; ++blk)                                                 \
        _Pragma("unroll")                                                               \
        for (int r = 0; r < 16; ++r) accO[blk][r] *= alpha;                             \
    }                                                                                   \
    float rs = 0.f;                                                                     \
    _Pragma("unroll")                                                                   \
    for (int kb = 0; kb < 2; ++kb)                                                      \
      _Pragma("unroll")                                                                 \
      for (int r = 0; r < 16; ++r) {                                                    \
        const float pv = exp2f(sc[kb][r] - m_run);                                      \
        sc[kb][r] = pv;                                                                 \
        rs += pv;                                                                       \
      }                                                                                 \
    rs += __shfl_xor(rs, 32, 64);                                                       \
    l_run += rs;                                                                        \
    bf16x8 pa[4];                                                                       \
    _Pragma("unroll")                                                                   \
    for (int ks = 0; ks < 4; ++ks) {                                                    \
      const int kb = ks >> 1;                                                           \
      const int base = 8 * (ks & 1);                                                    \
      unsigned int p00 = cvtpk_bf16(sc[kb][base + 0], sc[kb][base + 1]);                \
      unsigned int p01 = cvtpk_bf16(sc[kb][base + 2], sc[kb][base + 3]);                \
      unsigned int p10 = cvtpk_bf16(sc[kb][base + 4], sc[kb][base + 5]);                \
      unsigned int p11 = cvtpk_bf16(sc[kb][base + 6], sc[kb][base + 7]);                \
      asm volatile("v_permlane32_swap_b32 %0, %1" : "+v"(p00), "+v"(p10));              \
      asm volatile("v_permlane32_swap_b32 %0, %1" : "+v"(p01), "+v"(p11));              \
      unsigned int dw[4] = {p00, p01, p10, p11};                                        \
      pa[ks] = __builtin_bit_cast(bf16x8, *(u16x8*)dw);                                 \
    }                                                                                   \
    __builtin_amdgcn_s_setprio(1);                                                      \
    _Pragma("unroll")                                                                   \
    for (int blk = 0; blk < 2; ++blk)                                                   \
      _Pragma("unroll")                                                                 \
      for (int ks = 0; ks < 4; ++ks) {                                                  \
        const int row = blk * 32 + l31;                                                 \
        const int off = (row << 7) + ((32 * ks + 16 * hi) ^ ((row & 7) << 4));          \
        bf16x8 vb = *(const bf16x8*)((const char*)&Vt[cbuf_][s_][0] + off);             \
        accO[blk] = __builtin_amdgcn_mfma_f32_32x32x16_bf16(vb, pa[ks], accO[blk],      \
                                                            0, 0, 0);                   \
      }                                                                                 \
    __builtin_amdgcn_s_setprio(0);                                                      \
  }

  // prologue: stage tile 0 into buf 0
  {
    STAGE_K(0, 0);
    u16x8 pv0, pv1, pv2, pv3;
    LOAD_V(0, 0, pv0, pv1);
    LOAD_V(0, 1, pv2, pv3);
    WRITE_V(0, 0, pv0, pv1);
    WRITE_V(0, 1, pv2, pv3);
  }
  __syncthreads();

  for (int kt = 0; kt <= qt; ++kt) {
    const int cbuf = kt & 1, nbuf = cbuf ^ 1;
    const bool pre = (kt < qt);
    u16x8 nv0, nv1, nv2, nv3;
    if (pre) {
      STAGE_K(kt + 1, nbuf);
      LOAD_V(kt + 1, 0, nv0, nv1);
      LOAD_V(kt + 1, 1, nv2, nv3);
    }

    if (kt < qt) {
      SUBSTEP(cbuf, 0, false);
      SUBSTEP(cbuf, 1, false);
    } else {
      // diagonal tile: waves 0-1 need only sub0 (masked); waves 2-3 take
      // sub0 unmasked + sub1 masked. Wave-uniform branches.
      if (w < 2) {
        SUBSTEP(cbuf, 0, true);
      } else {
        SUBSTEP(cbuf, 0, false);
        SUBSTEP(cbuf, 1, true);
      }
    }

    if (pre) {
      WRITE_V(nbuf, 0, nv0, nv1);
      WRITE_V(nbuf, 1, nv2, nv3);
    }
    __syncthreads();
  }

  // ---- epilogue: O^T[d][q=l31] per lane; normalize, pack 4 contig d, store ----
  const float linv = 1.0f / l_run;
#pragma unroll
  for (int blk = 0; blk < 2; ++blk)
#pragma unroll
    for (int g = 0; g < 4; ++g) {
      const int dbase = 8 * g + 4 * hi + 32 * blk;
      u16x4 o;
#pragma unroll
      for (int e = 0; e < 4; ++e) o[e] = f2bf(accO[blk][4 * g + e] * linv);
      *(u16x4*)&Out[((size_t)(b2048 + q_g)) * 1024 + h * 64 + dbase] = o;
    }
}

// ---------------- launch ----------------
extern "C" void kernel_launch(void* const* d_in, const int* in_sizes, int n_in,
                              void* d_out, int out_size, void* d_ws, size_t ws_size,
                              hipStream_t stream) {
  const float* x    = (const float*)d_in[0];
  const float* wqkv = (const float*)d_in[1];
  const float* wo   = (const float*)d_in[2];
  const int*   pos  = (const int*)d_in[3];
  float* out = (float*)d_out;

  char* ws = (char*)d_ws;
  unsigned short* xb    = (unsigned short*)(ws);
  unsigned short* wqkvb = (unsigned short*)(ws + 16777216);
  unsigned short* wob   = (unsigned short*)(ws + 23068672);
  unsigned short* qkvb  = (unsigned short*)(ws + 25165824);
  unsigned short* Qr    = (unsigned short*)(ws + 75497472);
  unsigned short* Kr    = (unsigned short*)(ws + 92274688);
  unsigned short* att   = xb;

  cast_f32_bf16_k<<<2048, 256, 0, stream>>>(x, xb, 4 * 2048 * 1024);
  cast_f32_bf16_k<<<1024, 256, 0, stream>>>(wqkv, wqkvb, 3072 * 1024);
  cast_f32_bf16_k<<<512, 256, 0, stream>>>(wo, wob, 1024 * 1024);

  gemm_dbuf<unsigned short><<<dim3(24, 64), 256, 0, stream>>>(xb, wqkvb, qkvb, 8192, 3072, 1024);

  rope_repack<<<8192, 512, 0, stream>>>(qkvb, pos, Qr, Kr);

  attn_fwd<<<1024, 256, 0, stream>>>(Qr, Kr, qkvb, att);

  gemm_dbuf<float><<<dim3(8, 64), 256, 0, stream>>>(att, wob, out, 8192, 1024, 1024);
}

// Round 20
// 185.340 us; speedup vs baseline: 1.0830x; 1.0830x over previous
//
#include <hip/hip_runtime.h>

// MHA forward: x[4,2048,1024] f32, W_QKV[3072,1024] f32, W_O[1024,1024] f32,
// pos[2048] i32 -> out[4,2048,1024] f32.
// R14: attn reverted to validated R11 body (R12/R13 occupancy regressions);
//      three cast kernels fused into one launch. GEMMs (dbuf+T2), rope as R11.

typedef __attribute__((ext_vector_type(4)))  float          f32x4;
typedef __attribute__((ext_vector_type(16))) float          f32x16;
typedef __attribute__((ext_vector_type(8)))  __bf16         bf16x8;
typedef __attribute__((ext_vector_type(8)))  unsigned short u16x8;
typedef __attribute__((ext_vector_type(4)))  unsigned short u16x4;

__device__ __forceinline__ unsigned short f2bf(float f) {
  unsigned int u = __builtin_bit_cast(unsigned int, f);
  u = (u + 0x7fffu + ((u >> 16) & 1u)) >> 16;
  return (unsigned short)u;
}
__device__ __forceinline__ float bf2f(unsigned short b) {
  return __builtin_bit_cast(float, ((unsigned int)b) << 16);
}
__device__ __forceinline__ unsigned int cvtpk_bf16(float lo, float hi) {
  unsigned int r;
  asm("v_cvt_pk_bf16_f32 %0, %1, %2" : "=v"(r) : "v"(lo), "v"(hi));
  return r;
}
__device__ __forceinline__ void gload_lds16(const void* g, void* l) {
  __builtin_amdgcn_global_load_lds((const __attribute__((address_space(1))) void*)g,
                                   (__attribute__((address_space(3))) void*)l, 16, 0, 0);
}

// ---------------- fused cast f32 -> bf16 (x, W_QKV, W_O in one launch) ----------------
__device__ __forceinline__ void cast_region(const float* __restrict__ in,
                                            unsigned short* __restrict__ out, int n) {
  int i = (blockIdx.x * blockDim.x + threadIdx.x) * 4;
  const int stride = gridDim.x * blockDim.x * 4;
  for (; i < n; i += stride) {
    float4 v = *(const float4*)(in + i);
    u16x4 o = { f2bf(v.x), f2bf(v.y), f2bf(v.z), f2bf(v.w) };
    *(u16x4*)(out + i) = o;
  }
}
__global__ void cast3_k(const float* __restrict__ x, unsigned short* __restrict__ xb,
                        const float* __restrict__ wqkv, unsigned short* __restrict__ wqkvb,
                        const float* __restrict__ wo, unsigned short* __restrict__ wob) {
  cast_region(x, xb, 4 * 2048 * 1024);
  cast_region(wqkv, wqkvb, 3072 * 1024);
  cast_region(wo, wob, 1024 * 1024);
}

// ---------------- NT GEMM (dbuf + T2 swizzle): C = A * B^T ----------------
template <typename OutT>
__global__ __launch_bounds__(256) void gemm_dbuf(
    const unsigned short* __restrict__ A,
    const unsigned short* __restrict__ B,
    OutT* __restrict__ C,
    int M, int N, int K) {
  __shared__ unsigned short As[2][128 * 64];
  __shared__ unsigned short Bs[2][128 * 64];
  const int tid  = threadIdx.x;
  const int wid  = tid >> 6;
  const int lane = tid & 63;
  const int l15  = lane & 15, l4 = lane >> 4;
  const int wr   = wid >> 1, wc = wid & 1;
  const int flat = blockIdx.y * gridDim.x + blockIdx.x;
  const int cpx  = (gridDim.x * gridDim.y) >> 3;
  const int swz  = (flat & 7) * cpx + (flat >> 3);
  const int bx   = swz % gridDim.x, by = swz / gridDim.x;
  const int row0 = by * 128, col0 = bx * 128;
  const int wrb  = wr * 64, wcb = wc * 64;

  f32x4 acc[4][4];
  const f32x4 z = {0.f, 0.f, 0.f, 0.f};
#pragma unroll
  for (int m = 0; m < 4; ++m)
#pragma unroll
    for (int n = 0; n < 4; ++n) acc[m][n] = z;

#define STAGE_G(t_, buf_)                                                               \
  {                                                                                     \
    const int k0g = (t_) * 64;                                                          \
    _Pragma("unroll")                                                                   \
    for (int ig = 0; ig < 4; ++ig) {                                                    \
      const int flg = ig * 256 + tid;                                                   \
      const int rg  = flg >> 3;                                                         \
      const int cbg = (flg & 7) * 16;                                                   \
      const int scg = (cbg ^ ((rg & 7) << 4)) >> 1;                                     \
      gload_lds16(&A[(size_t)(row0 + rg) * K + k0g + scg],                              \
                  &As[buf_][rg * 64 + (cbg >> 1)]);                                     \
      gload_lds16(&B[(size_t)(col0 + rg) * K + k0g + scg],                              \
                  &Bs[buf_][rg * 64 + (cbg >> 1)]);                                     \
    }                                                                                   \
  }

  const int NT = K >> 6;
  STAGE_G(0, 0);
  __syncthreads();

  for (int t = 0; t < NT; ++t) {
    const int cbuf = t & 1;
    if (t + 1 < NT) STAGE_G(t + 1, cbuf ^ 1);
#pragma unroll
    for (int ks = 0; ks < 2; ++ks) {
      bf16x8 af[4], bfr[4];
#pragma unroll
      for (int m = 0; m < 4; ++m) {
        const int row = wrb + m * 16 + l15;
        const int off = (row << 7) + ((ks * 64 + l4 * 16) ^ ((row & 7) << 4));
        af[m] = *(const bf16x8*)((const char*)&As[cbuf][0] + off);
      }
#pragma unroll
      for (int n = 0; n < 4; ++n) {
        const int row = wcb + n * 16 + l15;
        const int off = (row << 7) + ((ks * 64 + l4 * 16) ^ ((row & 7) << 4));
        bfr[n] = *(const bf16x8*)((const char*)&Bs[cbuf][0] + off);
      }
      __builtin_amdgcn_s_setprio(1);
#pragma unroll
      for (int m = 0; m < 4; ++m)
#pragma unroll
        for (int n = 0; n < 4; ++n)
          acc[m][n] = __builtin_amdgcn_mfma_f32_16x16x32_bf16(af[m], bfr[n], acc[m][n], 0, 0, 0);
      __builtin_amdgcn_s_setprio(0);
    }
    __syncthreads();
  }
#undef STAGE_G

#pragma unroll
  for (int m = 0; m < 4; ++m) {
    const int row = row0 + wrb + m * 16 + l4 * 4;
#pragma unroll
    for (int n = 0; n < 4; ++n) {
      const int col = col0 + wcb + n * 16 + l15;
#pragma unroll
      for (int r = 0; r < 4; ++r) {
        float v = acc[m][n][r];
        if constexpr (sizeof(OutT) == 2)
          C[(size_t)(row + r) * N + col] = f2bf(v);
        else
          C[(size_t)(row + r) * N + col] = v;
      }
    }
  }
}

// ---------------- RoPE + repack qkv[B*S][3072] -> Q/K [B*H][S][64] ----------------
#define ATTN_SCL 0.18033688011112042f
#define NEG_L2_10K_32 (-0.41524101186092029f)  // -log2(10000)/32
__global__ __launch_bounds__(512) void rope_repack(
    const unsigned short* __restrict__ qkv,
    const int* __restrict__ pos,
    unsigned short* __restrict__ Qr,
    unsigned short* __restrict__ Kr) {
  const int bs = blockIdx.x;
  const int b  = bs >> 11, s = bs & 2047;
  const int t  = threadIdx.x;
  const int h  = t >> 5, kk = t & 31;
  const float p    = (float)pos[s];
  const float freq = exp2f((float)kk * NEG_L2_10K_32);
  float sn, c;
  __sincosf(p * freq, &sn, &c);
  const unsigned short* base = qkv + (size_t)bs * 3072;
  const size_t oidx = ((size_t)(b * 16 + h) * 2048 + s) * 64 + 2 * kk;
  float e = bf2f(base[h * 64 + 2 * kk]);
  float o = bf2f(base[h * 64 + 2 * kk + 1]);
  Qr[oidx]     = f2bf((c * e - sn * o) * ATTN_SCL);
  Qr[oidx + 1] = f2bf((sn * e + c * o) * ATTN_SCL);
  e = bf2f(base[1024 + h * 64 + 2 * kk]);
  o = bf2f(base[1024 + h * 64 + 2 * kk + 1]);
  Kr[oidx]     = f2bf(c * e - sn * o);
  Kr[oidx + 1] = f2bf(sn * e + c * o);
}

// ---------------- causal flash attention (validated R11 body) ----------------
// grid 1024 blocks x 256 thr (4 waves x 32 q-rows); KVBLK=64 double-buffered.
#define DEFER_THR 12.0f  // exp2-domain (~8.3 nats)

__global__ __launch_bounds__(256) void attn_fwd(
    const unsigned short* __restrict__ Qr,
    const unsigned short* __restrict__ Kr,
    const unsigned short* __restrict__ qkv,   // V source: [B*S][3072], col 2048+h*64
    unsigned short* __restrict__ Out) {       // [B*S][1024]
  __shared__ unsigned short Ks[2][64 * 64];   // swizzled: byte ^= (row&7)<<4
  __shared__ unsigned short Vt[2][64 * 64];   // [d][key], swizzled same
  const int flat = blockIdx.x;
  const int bh   = (flat & 7) * 8 + ((flat >> 3) & 7);
  const int qt   = 15 - (flat >> 6);          // longest-first
  const int tid  = threadIdx.x, w = tid >> 6, lane = tid & 63;
  const int l31  = lane & 31, hi = lane >> 5;
  const size_t hbase = (size_t)bh * 2048 * 64;
  const int b = bh >> 4, h = bh & 15;
  const int b2048 = b * 2048;
  const unsigned short* Vg = qkv + 2048 + h * 64;  // + row*3072 + d

  const int q_g   = qt * 128 + w * 32 + l31;  // this lane's query row
  const int mydt  = 2 * qt + (w >> 1);        // wave's diagonal tile
  const int ktmax = 2 * qt + 1;

  bf16x8 qf[4];
#pragma unroll
  for (int ks = 0; ks < 4; ++ks)
    qf[ks] = *(const bf16x8*)&Qr[hbase + (size_t)q_g * 64 + ks * 16 + hi * 8];

  f32x16 accO[2];
#pragma unroll
  for (int blk = 0; blk < 2; ++blk)
#pragma unroll
    for (int r = 0; r < 16; ++r) accO[blk][r] = 0.f;
  float m_run = -__builtin_inff(), l_run = 0.f;

  f32x16 zero16;
#pragma unroll
  for (int r = 0; r < 16; ++r) zero16[r] = 0.f;

  const int krow_in = w * 16 + (lane >> 3);
  const int kcb0    = (lane & 7) * 16;
  const int kp  = tid & 31;          // key pair 0..31
  const int vd0 = (tid >> 5) * 8;    // d 0..56
  const int vk0 = kp * 2;

#define STAGE_K(kt_, buf_)                                                              \
  {                                                                                     \
    _Pragma("unroll")                                                                   \
    for (int p = 0; p < 2; ++p) {                                                       \
      const int row = krow_in + p * 8;                                                  \
      const int scb = kcb0 ^ ((row & 7) << 4);                                          \
      gload_lds16(Kr + hbase + (size_t)((kt_) * 64 + row) * 64 + (scb >> 1),            \
                  &Ks[buf_][(w * 16 + p * 8) * 64]);                                    \
    }                                                                                   \
  }

#define LOAD_V(kt_, r0_, r1_)                                                           \
  {                                                                                     \
    const unsigned short* gv = Vg + (size_t)(b2048 + (kt_) * 64 + vk0) * 3072 + vd0;    \
    r0_ = *(const u16x8*)gv;                                                            \
    r1_ = *(const u16x8*)(gv + 3072);                                                   \
  }

#define WRITE_V(buf_, r0_, r1_)                                                         \
  {                                                                                     \
    _Pragma("unroll")                                                                   \
    for (int i = 0; i < 8; ++i) {                                                       \
      const int ba = ((vd0 + i) << 7) + ((vk0 * 2) ^ ((i & 7) << 4));                   \
      const unsigned int wv = (unsigned int)(r0_)[i] | ((unsigned int)(r1_)[i] << 16);  \
      *(unsigned int*)((char*)&Vt[buf_][0] + ba) = wv;                                  \
    }                                                                                   \
  }

  {
    STAGE_K(0, 0);
    u16x8 pv0, pv1;
    LOAD_V(0, pv0, pv1);
    WRITE_V(0, pv0, pv1);
  }
  __syncthreads();

  for (int kt = 0; kt <= ktmax; ++kt) {
    const int cbuf = kt & 1, nbuf = cbuf ^ 1;
    const bool pre = (kt < ktmax);
    u16x8 nv0, nv1;
    if (pre) {
      STAGE_K(kt + 1, nbuf);
      LOAD_V(kt + 1, nv0, nv1);
    }

    if (kt <= mydt) {  // wave-uniform causal skip
      f32x16 sc[2];
      __builtin_amdgcn_s_setprio(1);
#pragma unroll
      for (int kb = 0; kb < 2; ++kb) {
        {
          const int row = kb * 32 + l31;
          const int off = (row << 7) + ((16 * hi) ^ ((row & 7) << 4));
          bf16x8 kbf = *(const bf16x8*)((const char*)&Ks[cbuf][0] + off);
          sc[kb] = __builtin_amdgcn_mfma_f32_32x32x16_bf16(kbf, qf[0], zero16, 0, 0, 0);
        }
#pragma unroll
        for (int ks = 1; ks < 4; ++ks) {
          const int row = kb * 32 + l31;
          const int off = (row << 7) + ((32 * ks + 16 * hi) ^ ((row & 7) << 4));
          bf16x8 kbf = *(const bf16x8*)((const char*)&Ks[cbuf][0] + off);
          sc[kb] = __builtin_amdgcn_mfma_f32_32x32x16_bf16(kbf, qf[ks], sc[kb], 0, 0, 0);
        }
      }
      __builtin_amdgcn_s_setprio(0);

      if (kt == mydt) {
#pragma unroll
        for (int kb = 0; kb < 2; ++kb)
#pragma unroll
          for (int r = 0; r < 16; ++r) {
            const int key = (r & 3) + 8 * ((r >> 2) & 3) + 4 * hi + 32 * kb;
            if (kt * 64 + key > q_g) sc[kb][r] = -__builtin_inff();
          }
      }

      float pm[8];
#pragma unroll
      for (int i = 0; i < 8; ++i)
        pm[i] = fmaxf(fmaxf(sc[0][2 * i], sc[0][2 * i + 1]),
                      fmaxf(sc[1][2 * i], sc[1][2 * i + 1]));
      float rmax = fmaxf(fmaxf(fmaxf(pm[0], pm[1]), fmaxf(pm[2], pm[3])),
                         fmaxf(fmaxf(pm[4], pm[5]), fmaxf(pm[6], pm[7])));
      rmax = fmaxf(rmax, __shfl_xor(rmax, 32, 64));

      if (!__all(rmax <= m_run + DEFER_THR)) {
        const float mnew = fmaxf(m_run, rmax);
        const float alpha = exp2f(m_run - mnew);
        m_run = mnew;
        l_run *= alpha;
#pragma unroll
        for (int blk = 0; blk < 2; ++blk)
#pragma unroll
          for (int r = 0; r < 16; ++r) accO[blk][r] *= alpha;
      }

      float rs = 0.f;
#pragma unroll
      for (int kb = 0; kb < 2; ++kb)
#pragma unroll
        for (int r = 0; r < 16; ++r) {
          const float p = exp2f(sc[kb][r] - m_run);
          sc[kb][r] = p;
          rs += p;
        }
      rs += __shfl_xor(rs, 32, 64);
      l_run += rs;

      bf16x8 pa[4];
#pragma unroll
      for (int ks = 0; ks < 4; ++ks) {
        const int kb = ks >> 1;
        const int base = 8 * (ks & 1);
        unsigned int p00 = cvtpk_bf16(sc[kb][base + 0], sc[kb][base + 1]);
        unsigned int p01 = cvtpk_bf16(sc[kb][base + 2], sc[kb][base + 3]);
        unsigned int p10 = cvtpk_bf16(sc[kb][base + 4], sc[kb][base + 5]);
        unsigned int p11 = cvtpk_bf16(sc[kb][base + 6], sc[kb][base + 7]);
        asm volatile("v_permlane32_swap_b32 %0, %1" : "+v"(p00), "+v"(p10));
        asm volatile("v_permlane32_swap_b32 %0, %1" : "+v"(p01), "+v"(p11));
        unsigned int dw[4] = {p00, p01, p10, p11};
        pa[ks] = __builtin_bit_cast(bf16x8, *(u16x8*)dw);
      }

      __builtin_amdgcn_s_setprio(1);
#pragma unroll
      for (int blk = 0; blk < 2; ++blk)
#pragma unroll
        for (int ks = 0; ks < 4; ++ks) {
          const int row = blk * 32 + l31;
          const int off = (row << 7) + ((32 * ks + 16 * hi) ^ ((row & 7) << 4));
          bf16x8 vb = *(const bf16x8*)((const char*)&Vt[cbuf][0] + off);
          accO[blk] = __builtin_amdgcn_mfma_f32_32x32x16_bf16(vb, pa[ks], accO[blk], 0, 0, 0);
        }
      __builtin_amdgcn_s_setprio(0);
    }

    if (pre) WRITE_V(nbuf, nv0, nv1);
    __syncthreads();
  }

  const float linv = 1.0f / l_run;
#pragma unroll
  for (int blk = 0; blk < 2; ++blk)
#pragma unroll
    for (int g = 0; g < 4; ++g) {
      const int dbase = 8 * g + 4 * hi + 32 * blk;
      u16x4 o;
#pragma unroll
      for (int e = 0; e < 4; ++e) o[e] = f2bf(accO[blk][4 * g + e] * linv);
      *(u16x4*)&Out[((size_t)(b2048 + q_g)) * 1024 + h * 64 + dbase] = o;
    }
}

// ---------------- launch ----------------
extern "C" void kernel_launch(void* const* d_in, const int* in_sizes, int n_in,
                              void* d_out, int out_size, void* d_ws, size_t ws_size,
                              hipStream_t stream) {
  const float* x    = (const float*)d_in[0];
  const float* wqkv = (const float*)d_in[1];
  const float* wo   = (const float*)d_in[2];
  const int*   pos  = (const int*)d_in[3];
  float* out = (float*)d_out;

  char* ws = (char*)d_ws;
  unsigned short* xb    = (unsigned short*)(ws);
  unsigned short* wqkvb = (unsigned short*)(ws + 16777216);
  unsigned short* wob   = (unsigned short*)(ws + 23068672);
  unsigned short* qkvb  = (unsigned short*)(ws + 25165824);
  unsigned short* Qr    = (unsigned short*)(ws + 75497472);
  unsigned short* Kr    = (unsigned short*)(ws + 92274688);
  unsigned short* att   = xb;

  cast3_k<<<2048, 256, 0, stream>>>(x, xb, wqkv, wqkvb, wo, wob);

  gemm_dbuf<unsigned short><<<dim3(24, 64), 256, 0, stream>>>(xb, wqkvb, qkvb, 8192, 3072, 1024);

  rope_repack<<<8192, 512, 0, stream>>>(qkvb, pos, Qr, Kr);

  attn_fwd<<<1024, 256, 0, stream>>>(Qr, Kr, qkvb, att);

  gemm_dbuf<float><<<dim3(8, 64), 256, 0, stream>>>(att, wob, out, 8192, 1024, 1024);
}